// Round 1
// baseline (238.876 us; speedup 1.0000x reference)
//
#include <hip/hip_runtime.h>

#define VOCAB 4000
#define UNIQ 30000
#define MIDN 12
#define HID 256
#define OUT 768
#define BATCH 16
#define SEQ 2048

// ---------------------------------------------------------------------------
// Kernel 1: P[k][v][o] = sum_h E[v][h] * W[k*HID + h][o]   (k = 0,1,2)
// fp32 tiled GEMM: 64x64 tile, 256 threads, 4x4 outputs/thread, BK=16.
// ---------------------------------------------------------------------------
__global__ __launch_bounds__(256) void proj_gemm(
    const float* __restrict__ E, const float* __restrict__ W,
    float* __restrict__ P)
{
    const int k  = blockIdx.z;
    const int n0 = blockIdx.x * 64;
    const int m0 = blockIdx.y * 64;
    const float* Wk = W + (size_t)k * HID * OUT;
    float* Pk = P + (size_t)k * VOCAB * OUT;

    __shared__ float As[16][65];   // transposed: As[kk][m], +1 pad
    __shared__ float Bs[16][64];

    const int tid = threadIdx.x;   // 0..255
    const int tx = tid & 15;       // output col group
    const int ty = tid >> 4;       // output row group

    float acc[4][4] = {};

    for (int kt = 0; kt < HID; kt += 16) {
        // A tile: rows m0..m0+63, cols kt..kt+15  (float4 per thread)
        {
            int row = tid >> 2;            // 0..63
            int cg  = (tid & 3) * 4;       // 0,4,8,12
            int gm  = m0 + row;
            float4 a = make_float4(0.f, 0.f, 0.f, 0.f);
            if (gm < VOCAB)
                a = *reinterpret_cast<const float4*>(&E[(size_t)gm * HID + kt + cg]);
            As[cg + 0][row] = a.x;
            As[cg + 1][row] = a.y;
            As[cg + 2][row] = a.z;
            As[cg + 3][row] = a.w;
        }
        // B tile: rows kt..kt+15, cols n0..n0+63
        {
            int row = tid >> 4;            // 0..15
            int cg  = (tid & 15) * 4;      // 0..60
            float4 b = *reinterpret_cast<const float4*>(
                &Wk[(size_t)(kt + row) * OUT + n0 + cg]);
            *reinterpret_cast<float4*>(&Bs[row][cg]) = b;
        }
        __syncthreads();
        #pragma unroll
        for (int kk = 0; kk < 16; ++kk) {
            float a[4], b[4];
            #pragma unroll
            for (int i = 0; i < 4; ++i) a[i] = As[kk][ty * 4 + i];
            #pragma unroll
            for (int j = 0; j < 4; ++j) b[j] = Bs[kk][tx * 4 + j];
            #pragma unroll
            for (int i = 0; i < 4; ++i)
                #pragma unroll
                for (int j = 0; j < 4; ++j)
                    acc[i][j] += a[i] * b[j];
        }
        __syncthreads();
    }

    #pragma unroll
    for (int i = 0; i < 4; ++i) {
        int gm = m0 + ty * 4 + i;
        if (gm < VOCAB) {
            float4 v = make_float4(acc[i][0], acc[i][1], acc[i][2], acc[i][3]);
            *reinterpret_cast<float4*>(&Pk[(size_t)gm * OUT + n0 + tx * 4]) = v;
        }
    }
}

// ---------------------------------------------------------------------------
// Kernel 2: per-token gather-sum-scatter.
// out[b, l+1, :] = bias + P0[first[u]] + sum_m P1[mid[u,m]] + P2[last[u]],
// u = inv_i[b*SEQ + l].  One block per token, 192 threads x float4 = 768.
// ---------------------------------------------------------------------------
__global__ __launch_bounds__(192) void token_kernel(
    const float* __restrict__ P, const float* __restrict__ bias,
    const int* __restrict__ first, const int* __restrict__ mid,
    const int* __restrict__ last, const int* __restrict__ inv_i,
    float* __restrict__ out)
{
    const int t   = blockIdx.x;          // 0 .. BATCH*SEQ-1
    const int tid = threadIdx.x;         // 0..191
    const int o4  = tid * 4;
    const int u   = inv_i[t];            // block-uniform -> scalar loads below

    const float* P0 = P;
    const float* P1 = P + (size_t)VOCAB * OUT;
    const float* P2 = P + (size_t)2 * VOCAB * OUT;

    float4 acc = *reinterpret_cast<const float4*>(&bias[o4]);
    {
        int id = first[u];
        float4 v = *reinterpret_cast<const float4*>(&P0[(size_t)id * OUT + o4]);
        acc.x += v.x; acc.y += v.y; acc.z += v.z; acc.w += v.w;
    }
    #pragma unroll
    for (int m = 0; m < MIDN; ++m) {
        int id = mid[u * MIDN + m];
        float4 v = *reinterpret_cast<const float4*>(&P1[(size_t)id * OUT + o4]);
        acc.x += v.x; acc.y += v.y; acc.z += v.z; acc.w += v.w;
    }
    {
        int id = last[u];
        float4 v = *reinterpret_cast<const float4*>(&P2[(size_t)id * OUT + o4]);
        acc.x += v.x; acc.y += v.y; acc.z += v.z; acc.w += v.w;
    }

    const int b = t / SEQ;
    const int l = t % SEQ;
    *reinterpret_cast<float4*>(
        &out[((size_t)(b * (SEQ + 2) + l + 1)) * OUT + o4]) = acc;
}

// ---------------------------------------------------------------------------
// Kernel 3: zero the pad rows (l = 0 and l = SEQ+1 of each batch).
// ---------------------------------------------------------------------------
__global__ void zero_pads(float* __restrict__ out)
{
    int j = blockIdx.x * blockDim.x + threadIdx.x;   // float4 index
    const int n4 = OUT / 4;                          // 192
    if (j >= BATCH * 2 * n4) return;
    int b  = j / (2 * n4);
    int r  = (j / n4) & 1;
    int c4 = j % n4;
    int row = r ? (SEQ + 1) : 0;
    *reinterpret_cast<float4*>(
        &out[((size_t)(b * (SEQ + 2) + row)) * OUT + c4 * 4]) =
        make_float4(0.f, 0.f, 0.f, 0.f);
}

// ---------------------------------------------------------------------------
extern "C" void kernel_launch(void* const* d_in, const int* in_sizes, int n_in,
                              void* d_out, int out_size, void* d_ws, size_t ws_size,
                              hipStream_t stream)
{
    const float* emb    = (const float*)d_in[0];
    const float* head_w = (const float*)d_in[1];
    const float* head_b = (const float*)d_in[2];
    const int*   first  = (const int*)d_in[3];
    const int*   mid    = (const int*)d_in[4];
    const int*   last   = (const int*)d_in[5];
    const int*   inv_i  = (const int*)d_in[6];
    float* out = (float*)d_out;
    float* P   = (float*)d_ws;   // 3 * 4000 * 768 fp32 = 36.9 MB

    dim3 g1(OUT / 64, (VOCAB + 63) / 64, 3);
    proj_gemm<<<g1, 256, 0, stream>>>(emb, head_w, P);

    token_kernel<<<BATCH * SEQ, 192, 0, stream>>>(
        P, head_b, first, mid, last, inv_i, out);

    const int pad4 = BATCH * 2 * (OUT / 4);
    zero_pads<<<(pad4 + 255) / 256, 256, 0, stream>>>(out);
}

// Round 2
// 97.162 us; speedup vs baseline: 2.4585x; 2.4585x over previous
//
#include <hip/hip_runtime.h>

#define VOCAB 4000
#define UNIQ 30000
#define MIDN 12
#define HID 256
#define OUT 768
#define BATCH 16
#define SEQ 2048

typedef __attribute__((ext_vector_type(8))) short short8;   // 8 bf16 = 16B
typedef __attribute__((ext_vector_type(4))) float f32x4;
typedef __attribute__((ext_vector_type(4))) unsigned short u16x4;

__device__ __forceinline__ float bf2f(unsigned short u) {
    unsigned int x = ((unsigned int)u) << 16;
    float f;
    __builtin_memcpy(&f, &x, 4);
    return f;
}
__device__ __forceinline__ unsigned short f2bf(float f) {
    unsigned int x;
    __builtin_memcpy(&x, &f, 4);
    x += 0x7fff + ((x >> 16) & 1);   // round-to-nearest-even
    return (unsigned short)(x >> 16);
}

// ---------------------------------------------------------------------------
// Convert E (4000x256 fp32) -> bf16, same layout. 256000 float4 groups.
// ---------------------------------------------------------------------------
__global__ __launch_bounds__(256) void conv_e(
    const float* __restrict__ E, unsigned short* __restrict__ Ebf)
{
    int i = blockIdx.x * 256 + threadIdx.x;      // float4 index
    if (i >= VOCAB * HID / 4) return;
    f32x4 v = *reinterpret_cast<const f32x4*>(&E[i * 4]);
    u16x4 o;
    o.x = f2bf(v.x); o.y = f2bf(v.y); o.z = f2bf(v.z); o.w = f2bf(v.w);
    *reinterpret_cast<u16x4*>(&Ebf[i * 4]) = o;
}

// ---------------------------------------------------------------------------
// Convert W (768x768 fp32) -> Wt bf16 [3][768][256]: Wt[s][n][h] = W[s*256+h][n]
// ---------------------------------------------------------------------------
__global__ __launch_bounds__(256) void conv_w(
    const float* __restrict__ W, unsigned short* __restrict__ Wt)
{
    int idx = blockIdx.x * 256 + threadIdx.x;    // 0 .. 589823
    if (idx >= 3 * OUT * HID) return;
    int s = idx / (OUT * HID);
    int r = idx - s * (OUT * HID);
    int n = r >> 8;            // /256
    int h = r & 255;
    Wt[idx] = f2bf(W[(size_t)(s * HID + h) * OUT + n]);
}

// ---------------------------------------------------------------------------
// MFMA GEMM: P[s][m][n] (bf16) = sum_h Ebf[m][h] * W[s*256+h][n]
// A = Ebf rows (contiguous k), B = Wt[s] rows (contiguous k).
// 128x128 tile, 256 threads = 4 waves (2x2), BK=32, mfma_f32_16x16x32_bf16.
// ---------------------------------------------------------------------------
__global__ __launch_bounds__(256) void proj_mfma(
    const unsigned short* __restrict__ Ebf,
    const unsigned short* __restrict__ Wt,
    unsigned short* __restrict__ P)
{
    const int s  = blockIdx.z;
    const int n0 = blockIdx.x * 128;
    const int m0 = blockIdx.y * 128;
    const unsigned short* Wts = Wt + (size_t)s * OUT * HID;
    unsigned short* Ps = P + (size_t)s * VOCAB * OUT;

    // 80-byte row pitch (40 bf16): 16B-aligned b128 reads, 2-way-max bank alias
    __shared__ short As[128][40];
    __shared__ short Bs[128][40];

    const int tid  = threadIdx.x;
    const int lane = tid & 63;
    const int w    = tid >> 6;       // wave 0..3
    const int wm   = w >> 1;         // 0..1
    const int wn   = w & 1;          // 0..1
    const int lo   = lane & 15;
    const int hi   = lane >> 4;      // 0..3

    f32x4 acc[4][4] = {};

    for (int kt = 0; kt < HID; kt += 32) {
        // stage A: 128 rows x 32 k  (512 x short8 loads, 2 per thread)
        #pragma unroll
        for (int p = 0; p < 2; ++p) {
            int idx = p * 256 + tid;         // 0..511
            int row = idx >> 2;
            int ko  = (idx & 3) * 8;
            int gm  = m0 + row;
            short8 v = {};
            if (gm < VOCAB)
                v = *reinterpret_cast<const short8*>(&Ebf[(size_t)gm * HID + kt + ko]);
            *reinterpret_cast<short8*>(&As[row][ko]) = v;
        }
        // stage B: 128 cols x 32 k
        #pragma unroll
        for (int p = 0; p < 2; ++p) {
            int idx = p * 256 + tid;
            int col = idx >> 2;
            int ko  = (idx & 3) * 8;
            short8 v = *reinterpret_cast<const short8*>(
                &Wts[(size_t)(n0 + col) * HID + kt + ko]);
            *reinterpret_cast<short8*>(&Bs[col][ko]) = v;
        }
        __syncthreads();

        short8 a[4], b[4];
        #pragma unroll
        for (int f = 0; f < 4; ++f)
            a[f] = *reinterpret_cast<short8*>(&As[wm * 64 + f * 16 + lo][hi * 8]);
        #pragma unroll
        for (int f = 0; f < 4; ++f)
            b[f] = *reinterpret_cast<short8*>(&Bs[wn * 64 + f * 16 + lo][hi * 8]);
        #pragma unroll
        for (int fm = 0; fm < 4; ++fm)
            #pragma unroll
            for (int fn = 0; fn < 4; ++fn)
                acc[fm][fn] = __builtin_amdgcn_mfma_f32_16x16x32_bf16(
                    a[fm], b[fn], acc[fm][fn], 0, 0, 0);
        __syncthreads();
    }

    // epilogue: C/D layout col = lane&15, row = (lane>>4)*4 + reg
    #pragma unroll
    for (int fm = 0; fm < 4; ++fm) {
        #pragma unroll
        for (int fn = 0; fn < 4; ++fn) {
            #pragma unroll
            for (int r = 0; r < 4; ++r) {
                int gm = m0 + wm * 64 + fm * 16 + hi * 4 + r;
                int gn = n0 + wn * 64 + fn * 16 + lo;
                if (gm < VOCAB)
                    Ps[(size_t)gm * OUT + gn] = f2bf(acc[fm][fn][r]);
            }
        }
    }
}

// ---------------------------------------------------------------------------
// Per-token gather-sum-scatter over bf16 P.
// ---------------------------------------------------------------------------
__global__ __launch_bounds__(192) void token_kernel(
    const unsigned short* __restrict__ P, const float* __restrict__ bias,
    const int* __restrict__ first, const int* __restrict__ mid,
    const int* __restrict__ last, const int* __restrict__ inv_i,
    float* __restrict__ out)
{
    const int t   = blockIdx.x;
    const int tid = threadIdx.x;          // 0..191
    const int o4  = tid * 4;
    const int u   = inv_i[t];

    const unsigned short* P0 = P;
    const unsigned short* P1 = P + (size_t)VOCAB * OUT;
    const unsigned short* P2 = P + (size_t)2 * VOCAB * OUT;

    f32x4 acc = *reinterpret_cast<const f32x4*>(&bias[o4]);

    {
        int id = first[u];
        u16x4 v = *reinterpret_cast<const u16x4*>(&P0[(size_t)id * OUT + o4]);
        acc.x += bf2f(v.x); acc.y += bf2f(v.y); acc.z += bf2f(v.z); acc.w += bf2f(v.w);
    }
    #pragma unroll
    for (int m = 0; m < MIDN; ++m) {
        int id = mid[u * MIDN + m];
        u16x4 v = *reinterpret_cast<const u16x4*>(&P1[(size_t)id * OUT + o4]);
        acc.x += bf2f(v.x); acc.y += bf2f(v.y); acc.z += bf2f(v.z); acc.w += bf2f(v.w);
    }
    {
        int id = last[u];
        u16x4 v = *reinterpret_cast<const u16x4*>(&P2[(size_t)id * OUT + o4]);
        acc.x += bf2f(v.x); acc.y += bf2f(v.y); acc.z += bf2f(v.z); acc.w += bf2f(v.w);
    }

    const int b = t / SEQ;
    const int l = t - b * SEQ;
    float* dst = &out[((size_t)(b * (SEQ + 2) + l + 1)) * OUT + o4];
    __builtin_nontemporal_store(acc, reinterpret_cast<f32x4*>(dst));
}

// ---------------------------------------------------------------------------
__global__ void zero_pads(float* __restrict__ out)
{
    int j = blockIdx.x * blockDim.x + threadIdx.x;   // float4 index
    const int n4 = OUT / 4;                          // 192
    if (j >= BATCH * 2 * n4) return;
    int b  = j / (2 * n4);
    int r  = (j / n4) & 1;
    int c4 = j % n4;
    int row = r ? (SEQ + 1) : 0;
    f32x4 z = {};
    *reinterpret_cast<f32x4*>(
        &out[((size_t)(b * (SEQ + 2) + row)) * OUT + c4 * 4]) = z;
}

// ---------------------------------------------------------------------------
extern "C" void kernel_launch(void* const* d_in, const int* in_sizes, int n_in,
                              void* d_out, int out_size, void* d_ws, size_t ws_size,
                              hipStream_t stream)
{
    const float* emb    = (const float*)d_in[0];
    const float* head_w = (const float*)d_in[1];
    const float* head_b = (const float*)d_in[2];
    const int*   first  = (const int*)d_in[3];
    const int*   mid    = (const int*)d_in[4];
    const int*   last   = (const int*)d_in[5];
    const int*   inv_i  = (const int*)d_in[6];
    float* out = (float*)d_out;

    char* ws = (char*)d_ws;
    unsigned short* P   = (unsigned short*)ws;                  // 18,432,000 B
    unsigned short* Ebf = (unsigned short*)(ws + 18432000);     //  2,048,000 B
    unsigned short* Wt  = (unsigned short*)(ws + 20480000);     //  1,179,648 B

    conv_e<<<(VOCAB * HID / 4 + 255) / 256, 256, 0, stream>>>(emb, Ebf);
    conv_w<<<(3 * OUT * HID + 255) / 256, 256, 0, stream>>>(head_w, Wt);

    dim3 g1(OUT / 128, (VOCAB + 127) / 128, 3);   // 6 x 32 x 3
    proj_mfma<<<g1, 256, 0, stream>>>(Ebf, Wt, P);

    token_kernel<<<BATCH * SEQ, 192, 0, stream>>>(
        P, head_b, first, mid, last, inv_i, out);

    const int pad4 = BATCH * 2 * (OUT / 4);
    zero_pads<<<(pad4 + 255) / 256, 256, 0, stream>>>(out);
}

// Round 3
// 82.656 us; speedup vs baseline: 2.8900x; 1.1755x over previous
//
#include <hip/hip_runtime.h>

#define VOCAB 4000
#define UNIQ 30000
#define MIDN 12
#define HID 256
#define OUT 768
#define BATCH 16
#define SEQ 2048

#define NSLICE 8
#define SCOLS 96            // OUT / NSLICE
#define TOKS_PER_BLK 128
#define PASSES 8            // 16 tokens per pass * 8 = 128

typedef __attribute__((ext_vector_type(8))) short short8;   // 8 bf16 = 16B
typedef __attribute__((ext_vector_type(4))) float f32x4;

__device__ __forceinline__ float bf2f(unsigned short u) {
    unsigned int x = ((unsigned int)u) << 16;
    float f;
    __builtin_memcpy(&f, &x, 4);
    return f;
}
__device__ __forceinline__ unsigned short f2bf(float f) {
    unsigned int x;
    __builtin_memcpy(&x, &f, 4);
    x += 0x7fff + ((x >> 16) & 1);   // round-to-nearest-even
    return (unsigned short)(x >> 16);
}

// ---------------------------------------------------------------------------
// conv_w: W (768x768 fp32) -> Wt bf16 [3][768][256] via LDS transpose tiles.
// Wt[s][n][h] = W[s*256+h][n]. Coalesced on both sides.
// ---------------------------------------------------------------------------
__global__ __launch_bounds__(256) void conv_w(
    const float* __restrict__ W, unsigned short* __restrict__ Wt)
{
    __shared__ float T[32][33];
    const int s  = blockIdx.z;
    const int n0 = blockIdx.x * 32;
    const int h0 = blockIdx.y * 32;
    const int tx = threadIdx.x & 31;
    const int ty = threadIdx.x >> 5;          // 0..7

    #pragma unroll
    for (int k = 0; k < 4; ++k) {
        int h = ty + 8 * k;
        T[h][tx] = W[(size_t)(s * HID + h0 + h) * OUT + n0 + tx];
    }
    __syncthreads();
    #pragma unroll
    for (int k = 0; k < 4; ++k) {
        int n = ty + 8 * k;
        Wt[(size_t)(s * OUT + n0 + n) * HID + h0 + tx] = f2bf(T[tx][n]);
    }
}

// ---------------------------------------------------------------------------
// proj_mfma: P_sliced[sl][s][v][c] = sum_h E[v][h] * W[s*256+h][sl*96+c]
// A staged from fp32 E (converted in-register), B from Wt bf16.
// 128x128 tile, 4 waves, BK=32, mfma_f32_16x16x32_bf16.
// ---------------------------------------------------------------------------
__global__ __launch_bounds__(256) void proj_mfma(
    const float* __restrict__ E,
    const unsigned short* __restrict__ Wt,
    unsigned short* __restrict__ P)
{
    const int s  = blockIdx.z;
    const int n0 = blockIdx.x * 128;
    const int m0 = blockIdx.y * 128;
    const unsigned short* Wts = Wt + (size_t)s * OUT * HID;

    __shared__ short As[128][40];   // 80B pitch
    __shared__ short Bs[128][40];

    const int tid  = threadIdx.x;
    const int lane = tid & 63;
    const int w    = tid >> 6;
    const int wm   = w >> 1;
    const int wn   = w & 1;
    const int lo   = lane & 15;
    const int hi   = lane >> 4;

    f32x4 acc[4][4] = {};

    for (int kt = 0; kt < HID; kt += 32) {
        #pragma unroll
        for (int p = 0; p < 2; ++p) {
            int idx = p * 256 + tid;
            int row = idx >> 2;
            int ko  = (idx & 3) * 8;
            int gm  = m0 + row;
            f32x4 e0 = {}, e1 = {};
            if (gm < VOCAB) {
                e0 = *reinterpret_cast<const f32x4*>(&E[(size_t)gm * HID + kt + ko]);
                e1 = *reinterpret_cast<const f32x4*>(&E[(size_t)gm * HID + kt + ko + 4]);
            }
            short8 v;
            v[0] = (short)f2bf(e0.x); v[1] = (short)f2bf(e0.y);
            v[2] = (short)f2bf(e0.z); v[3] = (short)f2bf(e0.w);
            v[4] = (short)f2bf(e1.x); v[5] = (short)f2bf(e1.y);
            v[6] = (short)f2bf(e1.z); v[7] = (short)f2bf(e1.w);
            *reinterpret_cast<short8*>(&As[row][ko]) = v;
        }
        #pragma unroll
        for (int p = 0; p < 2; ++p) {
            int idx = p * 256 + tid;
            int col = idx >> 2;
            int ko  = (idx & 3) * 8;
            short8 v = *reinterpret_cast<const short8*>(
                &Wts[(size_t)(n0 + col) * HID + kt + ko]);
            *reinterpret_cast<short8*>(&Bs[col][ko]) = v;
        }
        __syncthreads();

        short8 a[4], b[4];
        #pragma unroll
        for (int f = 0; f < 4; ++f)
            a[f] = *reinterpret_cast<short8*>(&As[wm * 64 + f * 16 + lo][hi * 8]);
        #pragma unroll
        for (int f = 0; f < 4; ++f)
            b[f] = *reinterpret_cast<short8*>(&Bs[wn * 64 + f * 16 + lo][hi * 8]);
        #pragma unroll
        for (int fm = 0; fm < 4; ++fm)
            #pragma unroll
            for (int fn = 0; fn < 4; ++fn)
                acc[fm][fn] = __builtin_amdgcn_mfma_f32_16x16x32_bf16(
                    a[fm], b[fn], acc[fm][fn], 0, 0, 0);
        __syncthreads();
    }

    // epilogue into sliced layout: P[((sl*3 + s)*VOCAB + gm)*96 + c]
    // 16-col groups are 16-aligned and 96 = 6*16, so a group never crosses slices.
    #pragma unroll
    for (int fm = 0; fm < 4; ++fm) {
        #pragma unroll
        for (int fn = 0; fn < 4; ++fn) {
            #pragma unroll
            for (int r = 0; r < 4; ++r) {
                int gm = m0 + wm * 64 + fm * 16 + hi * 4 + r;
                int gn = n0 + wn * 64 + fn * 16 + lo;
                if (gm < VOCAB) {
                    unsigned int sl = (unsigned int)gn / SCOLS;
                    unsigned int cc = (unsigned int)gn - sl * SCOLS;
                    P[((size_t)(sl * 3 + s) * VOCAB + gm) * SCOLS + cc] =
                        f2bf(acc[fm][fn][r]);
                }
            }
        }
    }
}

// ---------------------------------------------------------------------------
// token_sliced: per-(token, column-slice) gather-sum-scatter.
// slice = blockIdx.x & 7 -> pinned to one XCD (round-robin dispatch), so each
// XCD's gather working set is 3*4000*96*2B = 2.3 MB < 4 MB L2.
// 192 threads = 16 tokens/pass * 12 lanes; lane covers 8 cols (short8).
// ---------------------------------------------------------------------------
__global__ __launch_bounds__(192) void token_sliced(
    const unsigned short* __restrict__ Ps, const float* __restrict__ bias,
    const int* __restrict__ first, const int* __restrict__ mid,
    const int* __restrict__ last, const int* __restrict__ inv_i,
    float* __restrict__ out)
{
    const int slice = blockIdx.x & (NSLICE - 1);
    const int chunk = blockIdx.x >> 3;
    const int tid   = threadIdx.x;
    const int grp   = tid / 12;          // 0..15
    const int lj    = tid - grp * 12;    // 0..11

    const unsigned short* P0 = Ps + (size_t)slice * 3 * VOCAB * SCOLS;
    const unsigned short* P1 = P0 + (size_t)VOCAB * SCOLS;
    const unsigned short* P2 = P0 + (size_t)2 * VOCAB * SCOLS;
    const int cbase = slice * SCOLS + lj * 8;

    const f32x4 bv0 = *reinterpret_cast<const f32x4*>(&bias[cbase]);
    const f32x4 bv1 = *reinterpret_cast<const f32x4*>(&bias[cbase + 4]);

    #pragma unroll 1
    for (int pass = 0; pass < PASSES; ++pass) {
        const int t = chunk * TOKS_PER_BLK + pass * 16 + grp;
        const int u = inv_i[t];

        float acc[8] = {bv0.x, bv0.y, bv0.z, bv0.w, bv1.x, bv1.y, bv1.z, bv1.w};

        {
            int id = first[u];
            short8 v = *reinterpret_cast<const short8*>(&P0[(size_t)id * SCOLS + lj * 8]);
            #pragma unroll
            for (int j = 0; j < 8; ++j) acc[j] += bf2f((unsigned short)v[j]);
        }
        #pragma unroll
        for (int m = 0; m < MIDN; ++m) {
            int id = mid[u * MIDN + m];
            short8 v = *reinterpret_cast<const short8*>(&P1[(size_t)id * SCOLS + lj * 8]);
            #pragma unroll
            for (int j = 0; j < 8; ++j) acc[j] += bf2f((unsigned short)v[j]);
        }
        {
            int id = last[u];
            short8 v = *reinterpret_cast<const short8*>(&P2[(size_t)id * SCOLS + lj * 8]);
            #pragma unroll
            for (int j = 0; j < 8; ++j) acc[j] += bf2f((unsigned short)v[j]);
        }

        const int b = t >> 11;           // / SEQ
        const int l = t & (SEQ - 1);
        float* dst = &out[((size_t)(b * (SEQ + 2) + l + 1)) * OUT + cbase];
        f32x4 o0 = {acc[0], acc[1], acc[2], acc[3]};
        f32x4 o1 = {acc[4], acc[5], acc[6], acc[7]};
        __builtin_nontemporal_store(o0, reinterpret_cast<f32x4*>(dst));
        __builtin_nontemporal_store(o1, reinterpret_cast<f32x4*>(dst + 4));
    }
}

// ---------------------------------------------------------------------------
__global__ void zero_pads(float* __restrict__ out)
{
    int j = blockIdx.x * blockDim.x + threadIdx.x;   // float4 index
    const int n4 = OUT / 4;                          // 192
    if (j >= BATCH * 2 * n4) return;
    int b  = j / (2 * n4);
    int r  = (j / n4) & 1;
    int c4 = j % n4;
    int row = r ? (SEQ + 1) : 0;
    f32x4 z = {};
    *reinterpret_cast<f32x4*>(
        &out[((size_t)(b * (SEQ + 2) + row)) * OUT + c4 * 4]) = z;
}

// ---------------------------------------------------------------------------
extern "C" void kernel_launch(void* const* d_in, const int* in_sizes, int n_in,
                              void* d_out, int out_size, void* d_ws, size_t ws_size,
                              hipStream_t stream)
{
    const float* emb    = (const float*)d_in[0];
    const float* head_w = (const float*)d_in[1];
    const float* head_b = (const float*)d_in[2];
    const int*   first  = (const int*)d_in[3];
    const int*   mid    = (const int*)d_in[4];
    const int*   last   = (const int*)d_in[5];
    const int*   inv_i  = (const int*)d_in[6];
    float* out = (float*)d_out;

    char* ws = (char*)d_ws;
    unsigned short* P  = (unsigned short*)ws;               // 18,432,000 B
    unsigned short* Wt = (unsigned short*)(ws + 18432000);  //  1,179,648 B

    dim3 gw(OUT / 32, HID / 32, 3);
    conv_w<<<gw, 256, 0, stream>>>(head_w, Wt);

    dim3 g1(OUT / 128, (VOCAB + 127) / 128, 3);   // 6 x 32 x 3
    proj_mfma<<<g1, 256, 0, stream>>>(emb, Wt, P);

    const int nblk = (BATCH * SEQ / TOKS_PER_BLK) * NSLICE;   // 2048
    token_sliced<<<nblk, 192, 0, stream>>>(
        P, head_b, first, mid, last, inv_i, out);

    const int pad4 = BATCH * 2 * (OUT / 4);
    zero_pads<<<(pad4 + 255) / 256, 256, 0, stream>>>(out);
}

// Round 4
// 76.015 us; speedup vs baseline: 3.1425x; 1.0874x over previous
//
#include <hip/hip_runtime.h>

#define VOCAB 4000
#define UNIQ 30000
#define MIDN 12
#define HID 256
#define OUT 768
#define BATCH 16
#define SEQ 2048

#define NSLICE 8
#define SCOLS 96            // OUT / NSLICE
#define TOKS_PER_BLK 128
#define PASSES 8            // 16 tokens per pass * 8 = 128

typedef __attribute__((ext_vector_type(8))) short short8;   // 8 bf16 = 16B
typedef __attribute__((ext_vector_type(4))) float f32x4;

__device__ __forceinline__ float bf2f(unsigned short u) {
    unsigned int x = ((unsigned int)u) << 16;
    float f;
    __builtin_memcpy(&f, &x, 4);
    return f;
}
__device__ __forceinline__ unsigned short f2bf(float f) {
    unsigned int x;
    __builtin_memcpy(&x, &f, 4);
    x += 0x7fff + ((x >> 16) & 1);   // round-to-nearest-even
    return (unsigned short)(x >> 16);
}

// ---------------------------------------------------------------------------
// build_ids: idsU[u][16] int16 = [first[u], mid[u,:]+4000, last[u]+8000, 0, 0]
// Folds the P-table offset into the row id so token gathers use one base.
// ---------------------------------------------------------------------------
__global__ __launch_bounds__(256) void build_ids(
    const int* __restrict__ first, const int* __restrict__ mid,
    const int* __restrict__ last, short* __restrict__ idsU)
{
    int u = blockIdx.x * 256 + threadIdx.x;
    if (u >= UNIQ) return;
    short ids[16];
    ids[0] = (short)first[u];
    #pragma unroll
    for (int m = 0; m < MIDN; ++m)
        ids[1 + m] = (short)(mid[u * MIDN + m] + VOCAB);
    ids[13] = (short)(last[u] + 2 * VOCAB);
    ids[14] = 0; ids[15] = 0;
    *reinterpret_cast<short8*>(&idsU[(size_t)u * 16])     = *reinterpret_cast<short8*>(&ids[0]);
    *reinterpret_cast<short8*>(&idsU[(size_t)u * 16 + 8]) = *reinterpret_cast<short8*>(&ids[8]);
}

// ---------------------------------------------------------------------------
// conv_w: W (768x768 fp32) -> Wt bf16 [3][768][256] via LDS transpose tiles.
// ---------------------------------------------------------------------------
__global__ __launch_bounds__(256) void conv_w(
    const float* __restrict__ W, unsigned short* __restrict__ Wt)
{
    __shared__ float T[32][33];
    const int s  = blockIdx.z;
    const int n0 = blockIdx.x * 32;
    const int h0 = blockIdx.y * 32;
    const int tx = threadIdx.x & 31;
    const int ty = threadIdx.x >> 5;

    #pragma unroll
    for (int k = 0; k < 4; ++k) {
        int h = ty + 8 * k;
        T[h][tx] = W[(size_t)(s * HID + h0 + h) * OUT + n0 + tx];
    }
    __syncthreads();
    #pragma unroll
    for (int k = 0; k < 4; ++k) {
        int n = ty + 8 * k;
        Wt[(size_t)(s * OUT + n0 + n) * HID + h0 + tx] = f2bf(T[tx][n]);
    }
}

// ---------------------------------------------------------------------------
// proj_mfma: P_sliced[sl][s][v][c] = sum_h E[v][h] * W[s*256+h][sl*96+c]
// 128x128 tile, 4 waves, BK=32, mfma_f32_16x16x32_bf16.
// ---------------------------------------------------------------------------
__global__ __launch_bounds__(256) void proj_mfma(
    const float* __restrict__ E,
    const unsigned short* __restrict__ Wt,
    unsigned short* __restrict__ P)
{
    const int s  = blockIdx.z;
    const int n0 = blockIdx.x * 128;
    const int m0 = blockIdx.y * 128;
    const unsigned short* Wts = Wt + (size_t)s * OUT * HID;

    __shared__ short As[128][40];   // 80B pitch
    __shared__ short Bs[128][40];

    const int tid  = threadIdx.x;
    const int lane = tid & 63;
    const int w    = tid >> 6;
    const int wm   = w >> 1;
    const int wn   = w & 1;
    const int lo   = lane & 15;
    const int hi   = lane >> 4;

    f32x4 acc[4][4] = {};

    for (int kt = 0; kt < HID; kt += 32) {
        #pragma unroll
        for (int p = 0; p < 2; ++p) {
            int idx = p * 256 + tid;
            int row = idx >> 2;
            int ko  = (idx & 3) * 8;
            int gm  = m0 + row;
            f32x4 e0 = {}, e1 = {};
            if (gm < VOCAB) {
                e0 = *reinterpret_cast<const f32x4*>(&E[(size_t)gm * HID + kt + ko]);
                e1 = *reinterpret_cast<const f32x4*>(&E[(size_t)gm * HID + kt + ko + 4]);
            }
            short8 v;
            v[0] = (short)f2bf(e0.x); v[1] = (short)f2bf(e0.y);
            v[2] = (short)f2bf(e0.z); v[3] = (short)f2bf(e0.w);
            v[4] = (short)f2bf(e1.x); v[5] = (short)f2bf(e1.y);
            v[6] = (short)f2bf(e1.z); v[7] = (short)f2bf(e1.w);
            *reinterpret_cast<short8*>(&As[row][ko]) = v;
        }
        #pragma unroll
        for (int p = 0; p < 2; ++p) {
            int idx = p * 256 + tid;
            int col = idx >> 2;
            int ko  = (idx & 3) * 8;
            short8 v = *reinterpret_cast<const short8*>(
                &Wts[(size_t)(n0 + col) * HID + kt + ko]);
            *reinterpret_cast<short8*>(&Bs[col][ko]) = v;
        }
        __syncthreads();

        short8 a[4], b[4];
        #pragma unroll
        for (int f = 0; f < 4; ++f)
            a[f] = *reinterpret_cast<short8*>(&As[wm * 64 + f * 16 + lo][hi * 8]);
        #pragma unroll
        for (int f = 0; f < 4; ++f)
            b[f] = *reinterpret_cast<short8*>(&Bs[wn * 64 + f * 16 + lo][hi * 8]);
        #pragma unroll
        for (int fm = 0; fm < 4; ++fm)
            #pragma unroll
            for (int fn = 0; fn < 4; ++fn)
                acc[fm][fn] = __builtin_amdgcn_mfma_f32_16x16x32_bf16(
                    a[fm], b[fn], acc[fm][fn], 0, 0, 0);
        __syncthreads();
    }

    #pragma unroll
    for (int fm = 0; fm < 4; ++fm) {
        #pragma unroll
        for (int fn = 0; fn < 4; ++fn) {
            #pragma unroll
            for (int r = 0; r < 4; ++r) {
                int gm = m0 + wm * 64 + fm * 16 + hi * 4 + r;
                int gn = n0 + wn * 64 + fn * 16 + lo;
                if (gm < VOCAB) {
                    unsigned int sl = (unsigned int)gn / SCOLS;
                    unsigned int cc = (unsigned int)gn - sl * SCOLS;
                    P[((size_t)(sl * 3 + s) * VOCAB + gm) * SCOLS + cc] =
                        f2bf(acc[fm][fn][r]);
                }
            }
        }
    }
}

// ---------------------------------------------------------------------------
// token_sliced v2: per-(token, column-slice) gather-sum-scatter.
//  - slice = blockIdx.x & 7 pins the 2.3 MB P-slice to one XCD's L2.
//  - all 8 pass-tokens' u prefetched at start (independent loads).
//  - packed id vector (2 loads) replaces 14 scalar id loads; next pass's ids
//    prefetched while current pass's 14 row gathers are in flight.
// ---------------------------------------------------------------------------
__global__ __launch_bounds__(192) void token_sliced(
    const unsigned short* __restrict__ Ps, const short* __restrict__ idsU,
    const float* __restrict__ bias, const int* __restrict__ inv_i,
    float* __restrict__ out)
{
    const int slice = blockIdx.x & (NSLICE - 1);
    const int chunk = blockIdx.x >> 3;
    const int tid   = threadIdx.x;
    const int grp   = tid / 12;          // 0..15
    const int lj    = tid - grp * 12;    // 0..11

    const unsigned short* P0 = Ps + (size_t)slice * 3 * VOCAB * SCOLS;
    const int cbase = slice * SCOLS + lj * 8;

    const f32x4 bv0 = *reinterpret_cast<const f32x4*>(&bias[cbase]);
    const f32x4 bv1 = *reinterpret_cast<const f32x4*>(&bias[cbase + 4]);

    // prefetch all pass tokens' unique-ids
    const int tbase = chunk * TOKS_PER_BLK + grp;
    int us[PASSES];
    #pragma unroll
    for (int p = 0; p < PASSES; ++p) us[p] = inv_i[tbase + p * 16];

    short8 idlo = *reinterpret_cast<const short8*>(&idsU[(size_t)us[0] * 16]);
    short8 idhi = *reinterpret_cast<const short8*>(&idsU[(size_t)us[0] * 16 + 8]);

    #pragma unroll 1
    for (int p = 0; p < PASSES; ++p) {
        // issue all 14 row gathers (independent)
        short8 row[14];
        #pragma unroll
        for (int s = 0; s < 14; ++s) {
            int idf = (unsigned short)(s < 8 ? idlo[s] : idhi[s - 8]);
            row[s] = *reinterpret_cast<const short8*>(
                &P0[(size_t)idf * SCOLS + lj * 8]);
        }
        // prefetch next pass's ids while gathers are in flight
        short8 nlo = idlo, nhi = idhi;
        if (p + 1 < PASSES) {
            nlo = *reinterpret_cast<const short8*>(&idsU[(size_t)us[p + 1] * 16]);
            nhi = *reinterpret_cast<const short8*>(&idsU[(size_t)us[p + 1] * 16 + 8]);
        }

        float acc[8] = {bv0.x, bv0.y, bv0.z, bv0.w, bv1.x, bv1.y, bv1.z, bv1.w};
        #pragma unroll
        for (int s = 0; s < 14; ++s)
            #pragma unroll
            for (int j = 0; j < 8; ++j)
                acc[j] += bf2f((unsigned short)row[s][j]);

        const int t = tbase + p * 16;
        const int b = t >> 11;           // / SEQ
        const int l = t & (SEQ - 1);
        float* dst = &out[((size_t)(b * (SEQ + 2) + l + 1)) * OUT + cbase];
        f32x4 o0 = {acc[0], acc[1], acc[2], acc[3]};
        f32x4 o1 = {acc[4], acc[5], acc[6], acc[7]};
        __builtin_nontemporal_store(o0, reinterpret_cast<f32x4*>(dst));
        __builtin_nontemporal_store(o1, reinterpret_cast<f32x4*>(dst + 4));

        idlo = nlo; idhi = nhi;
    }
}

// ---------------------------------------------------------------------------
__global__ void zero_pads(float* __restrict__ out)
{
    int j = blockIdx.x * blockDim.x + threadIdx.x;   // float4 index
    const int n4 = OUT / 4;                          // 192
    if (j >= BATCH * 2 * n4) return;
    int b  = j / (2 * n4);
    int r  = (j / n4) & 1;
    int c4 = j % n4;
    int row = r ? (SEQ + 1) : 0;
    f32x4 z = {};
    *reinterpret_cast<f32x4*>(
        &out[((size_t)(b * (SEQ + 2) + row)) * OUT + c4 * 4]) = z;
}

// ---------------------------------------------------------------------------
extern "C" void kernel_launch(void* const* d_in, const int* in_sizes, int n_in,
                              void* d_out, int out_size, void* d_ws, size_t ws_size,
                              hipStream_t stream)
{
    const float* emb    = (const float*)d_in[0];
    const float* head_w = (const float*)d_in[1];
    const float* head_b = (const float*)d_in[2];
    const int*   first  = (const int*)d_in[3];
    const int*   mid    = (const int*)d_in[4];
    const int*   last   = (const int*)d_in[5];
    const int*   inv_i  = (const int*)d_in[6];
    float* out = (float*)d_out;

    char* ws = (char*)d_ws;
    unsigned short* P    = (unsigned short*)ws;               // 18,432,000 B
    unsigned short* Wt   = (unsigned short*)(ws + 18432000);  //  1,179,648 B
    short*          idsU = (short*)(ws + 19611648);           //    960,000 B

    build_ids<<<(UNIQ + 255) / 256, 256, 0, stream>>>(first, mid, last, idsU);

    dim3 gw(OUT / 32, HID / 32, 3);
    conv_w<<<gw, 256, 0, stream>>>(head_w, Wt);

    dim3 g1(OUT / 128, (VOCAB + 127) / 128, 3);   // 6 x 32 x 3
    proj_mfma<<<g1, 256, 0, stream>>>(emb, Wt, P);

    const int nblk = (BATCH * SEQ / TOKS_PER_BLK) * NSLICE;   // 2048
    token_sliced<<<nblk, 192, 0, stream>>>(P, idsU, head_b, inv_i, out);

    const int pad4 = BATCH * 2 * (OUT / 4);
    zero_pads<<<(pad4 + 255) / 256, 256, 0, stream>>>(out);
}